// Round 11
// baseline (442.639 us; speedup 1.0000x reference)
//
#include <hip/hip_runtime.h>
#include <hip/hip_bf16.h>
#include <cstdint>

#define NEG (-1.0e30f)
#define INVLN2 1.44269504088896340736f
#define LN2    0.69314718055994530942f

typedef unsigned short u16;
typedef __attribute__((ext_vector_type(8))) short short8;
typedef __attribute__((ext_vector_type(4))) float f32x4;

typedef const __attribute__((address_space(1))) void cg_void;
typedef __attribute__((address_space(3))) void lds_void;

// dims
#define Bsz   32
#define Tlen  1000
#define Cdim  512
#define Vdim  2000
#define Udim  100
#define Mrows (Bsz * Tlen)   // 32000
#define Npad  2048
#define GROW  256            // G row stride in floats (1024 B)

// ws layout (bytes). G aliases a_bf (dead after gemm); klp aliases w_bf.
#define WS_ABF 0u
#define WS_G   0u
#define WS_WBF 32768000u                    // a_bf/G: 32000*1024
#define WS_KL  WS_WBF                       // 16*1000 floats, aliases w_bf
#define WS_Z   (WS_WBF + 2097152u)          // w_bf: 2048*512*2
#define WS_ACC (WS_Z + 128000000u)          // Z: 32000*2000*2; then accum: 2 floats

__device__ inline u16 f2bf(float x) {
  uint32_t u = __float_as_uint(x);
  uint32_t r = (u + 0x7fffu + ((u >> 16) & 1u)) >> 16;
  return (u16)r;
}
__device__ inline float bf2f(u16 u) {
  return __uint_as_float(((uint32_t)u) << 16);
}

// ---- DPP wave64 reductions (pure VALU, no LDS). Result valid in lane 63. ----
#define DPP_MAX_STAGE(m, ctrl) { \
    int _r = __builtin_amdgcn_update_dpp(__float_as_int(m), __float_as_int(m), \
                                         ctrl, 0xF, 0xF, false); \
    m = fmaxf(m, __int_as_float(_r)); }
#define DPP_SUM_STAGE(v, ctrl) { \
    int _r = __builtin_amdgcn_update_dpp(0, __float_as_int(v), \
                                         ctrl, 0xF, 0xF, true); \
    v += __int_as_float(_r); }

__device__ inline float dppMax64(float m) {
  DPP_MAX_STAGE(m, 0x111) DPP_MAX_STAGE(m, 0x112) DPP_MAX_STAGE(m, 0x114)
  DPP_MAX_STAGE(m, 0x118) DPP_MAX_STAGE(m, 0x142) DPP_MAX_STAGE(m, 0x143)
  return m;  // valid in lane 63
}
__device__ inline float dppSum64(float v) {
  DPP_SUM_STAGE(v, 0x111) DPP_SUM_STAGE(v, 0x112) DPP_SUM_STAGE(v, 0x114)
  DPP_SUM_STAGE(v, 0x118) DPP_SUM_STAGE(v, 0x142) DPP_SUM_STAGE(v, 0x143)
  return v;  // valid in lane 63
}

// shift value from lane-1 into this lane via DPP wave_shr:1 (VALU, no LDS).
__device__ inline float shiftup1(float x, float fill) {
  int r = __builtin_amdgcn_update_dpp(__float_as_int(fill), __float_as_int(x),
                                      0x138, 0xF, 0xF, false);
  return __int_as_float(r);
}

// ---------------- K1: fp32 -> bf16 conversion, vectorized ------------------
__global__ void convert_kernel(const float4* __restrict__ enc4, const float4* __restrict__ W4,
                               uint4* __restrict__ a4, uint4* __restrict__ w4,
                               const int* __restrict__ lens,
                               float* __restrict__ accum) {
  int idx = blockIdx.x * blockDim.x + threadIdx.x;
  int stride = gridDim.x * blockDim.x;
  if (idx == 0) { accum[0] = 0.0f; accum[1] = 0.0f; }
  const int nA = Mrows * Cdim / 8;
  const int nW = Vdim * Cdim / 8;
  const int nWp = Npad * Cdim / 8;
  for (int i = idx; i < nA; i += stride) {
    int row = i >> 6;                 // 64 groups of 8 per 512-col row
    int b = row / 1000;
    int t = row - b * 1000;
    if (t >= lens[b]) continue;       // dead row: Z never read
    float4 x = enc4[2 * i], y = enc4[2 * i + 1];
    uint4 o;
    o.x = (uint32_t)f2bf(x.x) | ((uint32_t)f2bf(x.y) << 16);
    o.y = (uint32_t)f2bf(x.z) | ((uint32_t)f2bf(x.w) << 16);
    o.z = (uint32_t)f2bf(y.x) | ((uint32_t)f2bf(y.y) << 16);
    o.w = (uint32_t)f2bf(y.z) | ((uint32_t)f2bf(y.w) << 16);
    a4[i] = o;
  }
  for (int i = idx; i < nWp; i += stride) {
    uint4 o = {0, 0, 0, 0};
    if (i < nW) {
      float4 x = W4[2 * i], y = W4[2 * i + 1];
      o.x = (uint32_t)f2bf(x.x) | ((uint32_t)f2bf(x.y) << 16);
      o.y = (uint32_t)f2bf(x.z) | ((uint32_t)f2bf(x.w) << 16);
      o.z = (uint32_t)f2bf(y.x) | ((uint32_t)f2bf(y.y) << 16);
      o.w = (uint32_t)f2bf(y.z) | ((uint32_t)f2bf(y.w) << 16);
    }
    w4[i] = o;
  }
}

// ---------------- K2: bf16 GEMM (A: 32000x512, W: 2048x512, C = A*W^T) -----
// Round-10/11: LDS-FREE. r7/r8/r9 post-mortem: three different pipeline
// structures (0-deep drain, counted-vmcnt 3-buffer, 2-phase dbuf) all pinned
// at ~87 us / MfmaUtil 25% -> the shared resource is the bound. Arithmetic:
// per K-step per block, 64 ds_read_b128 (A,B fragments each read by 2 waves)
// + 32 KB gload_lds writes ~= 750+ cyc of LDS port traffic vs ~310 cyc of
// matrix-pipe work -> predicted 20-30% MfmaUtil. Fix: load MFMA fragments
// DIRECTLY from global -- lane's A-frag for K-chunk c is
// A[row*512 + c*32 + quad*8]; per instruction a wave touches 16 rows x 64
// contiguous bytes (fully-used 64B lines); per-lane offsets loop-invariant
// (8 address streams, immediate offsets). B (2 MB) is L2-resident; A-tiles
// shared by 16 same-XCD blocks (swizzle kept) -> L2 hits, HBM unchanged.
// Zero LDS, zero barriers: pure register dataflow, compiler pipelines
// freely; occupancy VGPR-limited. Fragment/MFMA order bit-identical to r9
// (staging algebra: LDS[g][c8]=A[g][(c8^(g&7))*8] read at (kk*4+quad)^(row&7)
// == A[row][c*32+quad*8] -- exactly the direct-load address).
__global__ __launch_bounds__(256) void gemm_kernel(const u16* __restrict__ A,
                                                   const u16* __restrict__ Wb,
                                                   const int* __restrict__ lens,
                                                   u16* __restrict__ Z) {
  const int id = blockIdx.x;
  const int c = id >> 7, r = id & 127;
  int mTile, nTile;
  if (c < 31) { mTile = c * 8 + (r & 7); nTile = r >> 3; }
  else        { mTile = 248 + (r & 1);   nTile = r >> 1; }   // tail ids 3968..3999
  const int mBase = mTile * 128;
  const int nBase = nTile * 128;
  {
    int bSeq = mBase / 1000;
    int t0 = mBase - bSeq * 1000;
    if (t0 <= 872 && t0 >= lens[bSeq]) return;   // whole tile dead
  }

  const int tid = threadIdx.x;
  const int wave = tid >> 6;
  const int lane = tid & 63;
  const int m_lane = lane & 15;
  const int quad = lane >> 4;

  // per-lane fragment base pointers (loop-invariant)
  const u16* Ap = A + ((size_t)(mBase + (wave >> 1) * 64 + m_lane) << 9) + quad * 8;
  const u16* Bp = Wb + ((size_t)(nBase + (wave & 1) * 64 + m_lane) << 9) + quad * 8;

  f32x4 acc[4][4];
  const f32x4 zero4 = {0.0f, 0.0f, 0.0f, 0.0f};
  #pragma unroll
  for (int i = 0; i < 4; ++i)
    #pragma unroll
    for (int j = 0; j < 4; ++j) acc[i][j] = zero4;

  #pragma unroll
  for (int kc = 0; kc < 16; ++kc) {            // 16 K-chunks of 32
    short8 af[4], bfv[4];
    #pragma unroll
    for (int mi = 0; mi < 4; ++mi)
      af[mi] = *(const short8*)(Ap + (size_t)mi * 16 * 512 + kc * 32);
    #pragma unroll
    for (int ni = 0; ni < 4; ++ni)
      bfv[ni] = *(const short8*)(Bp + (size_t)ni * 16 * 512 + kc * 32);
    __builtin_amdgcn_s_setprio(1);
    #pragma unroll
    for (int mi = 0; mi < 4; ++mi)
      #pragma unroll
      for (int ni = 0; ni < 4; ++ni)
        acc[mi][ni] = __builtin_amdgcn_mfma_f32_16x16x32_bf16(af[mi], bfv[ni],
                                                              acc[mi][ni], 0, 0, 0);
    __builtin_amdgcn_s_setprio(0);
  }

  #pragma unroll
  for (int ni = 0; ni < 4; ++ni) {
    int col = nBase + (wave & 1) * 64 + ni * 16 + m_lane;
    if (col < Vdim) {
      #pragma unroll
      for (int mi = 0; mi < 4; ++mi) {
        int row0 = mBase + (wave >> 1) * 64 + mi * 16 + quad * 4;
        #pragma unroll
        for (int rg = 0; rg < 4; ++rg)
          Z[(size_t)(row0 + rg) * Vdim + col] = f2bf(acc[mi][ni][rg]);
      }
    }
  }
}

// ---------------- K3: fused softmax stats + CR loss + CTC gather -----------
__global__ __launch_bounds__(256) void cr_stats_kernel(const u16* __restrict__ Z,
                                                       const float* __restrict__ bias,
                                                       const int* __restrict__ lens,
                                                       const int* __restrict__ targets,
                                                       const int* __restrict__ tlens,
                                                       float* __restrict__ G,
                                                       float* __restrict__ klp) {
  int bp = blockIdx.x;   // 0..15
  int t = blockIdx.y;    // 0..999
  int tid = threadIdx.x;
  size_t r1 = (size_t)bp * Tlen + t;
  if (t >= lens[bp]) {               // dead block: G rows unread, KL masked
    if (tid == 0) klp[r1] = 0.0f;
    return;
  }
  int wave = tid >> 6, lane = tid & 63;
  size_t r2 = r1 + (size_t)16 * Tlen;
  const u16* z1 = Z + r1 * Vdim;
  const u16* z2 = Z + r2 * Vdim;

  __shared__ __attribute__((aligned(16))) float ls1[Vdim];
  __shared__ __attribute__((aligned(16))) float ls2[Vdim];
  __shared__ float red[8];

  const int c0 = tid * 8;            // this thread's 8 contiguous columns
  float v1[8], v2[8], e1[8], e2[8];
  float mx1 = NEG, mx2 = NEG;
  if (c0 < Vdim) {                   // tid < 250 (2000 = 250*8)
    short8 za = *(const short8*)&z1[c0];
    short8 zb = *(const short8*)&z2[c0];
    float4 b0 = *(const float4*)&bias[c0];
    float4 b1 = *(const float4*)&bias[c0 + 4];
    float bb[8] = {b0.x, b0.y, b0.z, b0.w, b1.x, b1.y, b1.z, b1.w};
    #pragma unroll
    for (int j = 0; j < 8; ++j) {
      v1[j] = bf2f((u16)za[j]) + bb[j];
      v2[j] = bf2f((u16)zb[j]) + bb[j];
      mx1 = fmaxf(mx1, v1[j]);
      mx2 = fmaxf(mx2, v2[j]);
    }
    *(float4*)&ls1[c0]     = (float4){v1[0], v1[1], v1[2], v1[3]};
    *(float4*)&ls1[c0 + 4] = (float4){v1[4], v1[5], v1[6], v1[7]};
    *(float4*)&ls2[c0]     = (float4){v2[0], v2[1], v2[2], v2[3]};
    *(float4*)&ls2[c0 + 4] = (float4){v2[4], v2[5], v2[6], v2[7]};
  } else {
    #pragma unroll
    for (int j = 0; j < 8; ++j) { v1[j] = NEG; v2[j] = NEG; }
  }
  float w1 = dppMax64(mx1), w2 = dppMax64(mx2);
  if (lane == 63) { red[wave] = w1; red[4 + wave] = w2; }
  __syncthreads();
  float M1 = fmaxf(fmaxf(red[0], red[1]), fmaxf(red[2], red[3]));
  float M2 = fmaxf(fmaxf(red[4], red[5]), fmaxf(red[6], red[7]));
  __syncthreads();
  float s1 = 0.0f, s2 = 0.0f;
  #pragma unroll
  for (int j = 0; j < 8; ++j) {
    e1[j] = expf(v1[j] - M1);   // 0 for padded cols (v = NEG)
    e2[j] = expf(v2[j] - M2);
    s1 += e1[j];
    s2 += e2[j];
  }
  s1 = dppSum64(s1); s2 = dppSum64(s2);
  if (lane == 63) { red[wave] = s1; red[4 + wave] = s2; }
  __syncthreads();
  float S1 = red[0] + red[1] + red[2] + red[3];
  float S2 = red[4] + red[5] + red[6] + red[7];
  float c1 = M1 + logf(S1);
  float c2 = M2 + logf(S2);
  float inv1 = 1.0f / S1;
  float inv2 = 1.0f / S2;

  if (tid < 64) {
    int i1 = min(2 * tid, Udim - 1);
    int i3 = min(2 * tid + 1, Udim - 1);
    int t1a = targets[bp * Udim + i1];
    int t1b = targets[bp * Udim + i3];
    int t2a = targets[(bp + 16) * Udim + i1];
    int t2b = targets[(bp + 16) * Udim + i3];
    int tl1 = tlens[bp];
    int tl2 = tlens[bp + 16];
    // LINEAR probabilities; labels past this sequence's target length -> 0
    // (keeps lattice states s > 2*tl exactly 0 in the scan).
    float4 g1 = {(2 * tid < tl1) ? expf(ls1[t1a] - c1) : 0.0f,
                 (2 * tid + 1 < tl1) ? expf(ls1[t1b] - c1) : 0.0f,
                 expf(ls1[0] - c1), 0.0f};
    float4 g2 = {(2 * tid < tl2) ? expf(ls2[t2a] - c2) : 0.0f,
                 (2 * tid + 1 < tl2) ? expf(ls2[t2b] - c2) : 0.0f,
                 expf(ls2[0] - c2), 0.0f};
    *(float4*)(G + r1 * GROW + 4 * tid) = g1;
    *(float4*)(G + r2 * GROW + 4 * tid) = g2;
  }

  float f = 0.0f;
  #pragma unroll
  for (int j = 0; j < 8; ++j) {
    // p = expf(v - c) == e * (1/S), exactly; padded cols: (0-0)*(NEG-NEG)=0.
    float p1 = e1[j] * inv1;
    float p2 = e2[j] * inv2;
    f += (p1 - p2) * (v1[j] - v2[j]);
  }
  __syncthreads();
  f = dppSum64(f);
  if (lane == 63) red[wave] = f;
  __syncthreads();
  if (tid == 0) {
    klp[r1] = red[0] + red[1] + red[2] + red[3];  // plain store, no atomic
  }
}

// ---------------- K4: CTC forward scan, one wave per sequence --------------
#define DECL3(p, i) float p##i##x, p##i##y, p##i##b;
#define LOADR(p, i, row) { float4 v = *(const float4*)(gb + (size_t)(row) * GROW + 4 * lane); \
    p##i##x = v.x; p##i##y = v.y; p##i##b = v.z; }

// unconditional step (main loop: every step here satisfies t < len)
#define COMPU(p, i) { \
    float pX = p##i##x, pY = p##i##y, pB = p##i##b; \
    float p3 = shiftup1(a3, 0.0f); \
    float t01 = a1 + a0; \
    float t23 = a3 + a2; \
    float n0 = (a0 + p3) * pB; \
    float n1 = fmaf(p3, fm1, t01) * pX; \
    float n2 = (a2 + a1) * pB; \
    float n3 = fmaf(a1, fm3, t23) * pY; \
    a0 = n0; a1 = n1; a2 = n2; a3 = n3; }

// guarded step (tail: freeze once past this sequence's input length)
#define COMPA(p, i, off) { \
    float pX = p##i##x, pY = p##i##y, pB = p##i##b; \
    float p3 = shiftup1(a3, 0.0f); \
    float t01 = a1 + a0; \
    float t23 = a3 + a2; \
    float n0 = (a0 + p3) * pB; \
    float n1 = fmaf(p3, fm1, t01) * pX; \
    float n2 = (a2 + a1) * pB; \
    float n3 = fmaf(a1, fm3, t23) * pY; \
    bool act = (t + (off)) < len; \
    a0 = act ? n0 : a0; a1 = act ? n1 : a1; \
    a2 = act ? n2 : a2; a3 = act ? n3 : a3; }

// DPP wave-max step: bound_ctrl=true fills invalid lanes with 0 (all a >= 0)
#define DPPMAX(m, ctrl) { int _r = __builtin_amdgcn_update_dpp(0,              \
      __float_as_int(m), ctrl, 0xF, 0xF, true);                               \
    m = fmaxf(m, __int_as_float(_r)); }

// Exact kill of states that cannot reach the readout, then exact power-of-2
// rescale pinning the wave max at ~2^100; logScale tracks the total scale.
#define RESCALE_KILL(tdone) {                                                 \
    int R = len - 1 - (tdone); R = R < 0 ? 0 : R;                             \
    int lo = end1 - 2 * R;                                                    \
    a0 = (base4 + 0 >= lo) ? a0 : 0.0f;                                       \
    a1 = (base4 + 1 >= lo) ? a1 : 0.0f;                                       \
    a2 = (base4 + 2 >= lo) ? a2 : 0.0f;                                       \
    a3 = (base4 + 3 >= lo) ? a3 : 0.0f;                                       \
    float m = fmaxf(fmaxf(a0, a1), fmaxf(a2, a3));                            \
    DPPMAX(m, 0x111) DPPMAX(m, 0x112) DPPMAX(m, 0x114) DPPMAX(m, 0x118)       \
    DPPMAX(m, 0x142) DPPMAX(m, 0x143)                                         \
    uint32_t mb = (uint32_t)__builtin_amdgcn_readlane(__float_as_int(m), 63); \
    int e = (int)((mb >> 23) & 0xffu);                                        \
    int sh = 227 - e;                                                         \
    sh = sh > 127 ? 127 : (sh < -126 ? -126 : sh);                            \
    float sc = __uint_as_float((uint32_t)(sh + 127) << 23);                   \
    a0 *= sc; a1 *= sc; a2 *= sc; a3 *= sc;                                   \
    logScale -= sh; }

#define LOAD32(p, base) \
    LOADR(p, 0,  (base) + 0)  LOADR(p, 1,  (base) + 1)  LOADR(p, 2,  (base) + 2)  LOADR(p, 3,  (base) + 3)  \
    LOADR(p, 4,  (base) + 4)  LOADR(p, 5,  (base) + 5)  LOADR(p, 6,  (base) + 6)  LOADR(p, 7,  (base) + 7)  \
    LOADR(p, 8,  (base) + 8)  LOADR(p, 9,  (base) + 9)  LOADR(p, 10, (base) + 10) LOADR(p, 11, (base) + 11) \
    LOADR(p, 12, (base) + 12) LOADR(p, 13, (base) + 13) LOADR(p, 14, (base) + 14) LOADR(p, 15, (base) + 15) \
    LOADR(p, 16, (base) + 16) LOADR(p, 17, (base) + 17) LOADR(p, 18, (base) + 18) LOADR(p, 19, (base) + 19) \
    LOADR(p, 20, (base) + 20) LOADR(p, 21, (base) + 21) LOADR(p, 22, (base) + 22) LOADR(p, 23, (base) + 23) \
    LOADR(p, 24, (base) + 24) LOADR(p, 25, (base) + 25) LOADR(p, 26, (base) + 26) LOADR(p, 27, (base) + 27) \
    LOADR(p, 28, (base) + 28) LOADR(p, 29, (base) + 29) LOADR(p, 30, (base) + 30) LOADR(p, 31, (base) + 31)

#define COMPU32(p, tb) \
    COMPU(p, 0)  COMPU(p, 1)  COMPU(p, 2)  COMPU(p, 3)  \
    COMPU(p, 4)  COMPU(p, 5)  COMPU(p, 6)  COMPU(p, 7)  \
    RESCALE_KILL((tb) + 7) \
    COMPU(p, 8)  COMPU(p, 9)  COMPU(p, 10) COMPU(p, 11) \
    COMPU(p, 12) COMPU(p, 13) COMPU(p, 14) COMPU(p, 15) \
    RESCALE_KILL((tb) + 15) \
    COMPU(p, 16) COMPU(p, 17) COMPU(p, 18) COMPU(p, 19) \
    COMPU(p, 20) COMPU(p, 21) COMPU(p, 22) COMPU(p, 23) \
    RESCALE_KILL((tb) + 23) \
    COMPU(p, 24) COMPU(p, 25) COMPU(p, 26) COMPU(p, 27) \
    COMPU(p, 28) COMPU(p, 29) COMPU(p, 30) COMPU(p, 31) \
    RESCALE_KILL((tb) + 31)

#define COMPA32(p, o) \
    COMPA(p, 0,  (o) + 0)  COMPA(p, 1,  (o) + 1)  COMPA(p, 2,  (o) + 2)  COMPA(p, 3,  (o) + 3)  \
    COMPA(p, 4,  (o) + 4)  COMPA(p, 5,  (o) + 5)  COMPA(p, 6,  (o) + 6)  COMPA(p, 7,  (o) + 7)  \
    RESCALE_KILL(t + (o) + 7) \
    COMPA(p, 8,  (o) + 8)  COMPA(p, 9,  (o) + 9)  COMPA(p, 10, (o) + 10) COMPA(p, 11, (o) + 11) \
    COMPA(p, 12, (o) + 12) COMPA(p, 13, (o) + 13) COMPA(p, 14, (o) + 14) COMPA(p, 15, (o) + 15) \
    RESCALE_KILL(t + (o) + 15) \
    COMPA(p, 16, (o) + 16) COMPA(p, 17, (o) + 17) COMPA(p, 18, (o) + 18) COMPA(p, 19, (o) + 19) \
    COMPA(p, 20, (o) + 20) COMPA(p, 21, (o) + 21) COMPA(p, 22, (o) + 22) COMPA(p, 23, (o) + 23) \
    RESCALE_KILL(t + (o) + 23) \
    COMPA(p, 24, (o) + 24) COMPA(p, 25, (o) + 25) COMPA(p, 26, (o) + 26) COMPA(p, 27, (o) + 27) \
    COMPA(p, 28, (o) + 28) COMPA(p, 29, (o) + 29) COMPA(p, 30, (o) + 30) COMPA(p, 31, (o) + 31) \
    RESCALE_KILL(t + (o) + 31)

#define DECL32(p) \
    DECL3(p, 0)  DECL3(p, 1)  DECL3(p, 2)  DECL3(p, 3)  DECL3(p, 4)  DECL3(p, 5)  DECL3(p, 6)  DECL3(p, 7)  \
    DECL3(p, 8)  DECL3(p, 9)  DECL3(p, 10) DECL3(p, 11) DECL3(p, 12) DECL3(p, 13) DECL3(p, 14) DECL3(p, 15) \
    DECL3(p, 16) DECL3(p, 17) DECL3(p, 18) DECL3(p, 19) DECL3(p, 20) DECL3(p, 21) DECL3(p, 22) DECL3(p, 23) \
    DECL3(p, 24) DECL3(p, 25) DECL3(p, 26) DECL3(p, 27) DECL3(p, 28) DECL3(p, 29) DECL3(p, 30) DECL3(p, 31)

__global__ __launch_bounds__(64, 1) void ctc_kernel(const float* __restrict__ G,
                                                    const int* __restrict__ targets,
                                                    const int* __restrict__ lens,
                                                    const int* __restrict__ tlens,
                                                    float* __restrict__ accum) {
  int b = blockIdx.x;
  int lane = threadIdx.x;
  const int* tgt = targets + b * Udim;
  int i1 = min(2 * lane, Udim - 1);
  int i3 = min(2 * lane + 1, Udim - 1);
  int l1 = tgt[i1];
  int l3 = tgt[i3];
  int lm1 = tgt[min(max(2 * lane - 1, 0), Udim - 1)];
  const float fm1 = ((lane >= 1) && (l1 != lm1)) ? 1.0f : 0.0f;  // skip1 mask
  const float fm3 = (l3 != l1) ? 1.0f : 0.0f;                    // skip3 mask
  int len = lens[b];
  int tl = tlens[b];
  const int end1 = 2 * tl - 1;       // readout states are end1 and end1+1
  const int base4 = 4 * lane;        // this lane owns states base4..base4+3
  const float* gb = G + (size_t)b * Tlen * GROW;

  // t=0 init (linear space): lane0's float4 = {p(tgt0), p(tgt1), blank, 0}
  float4 v0 = *(const float4*)(gb + 4 * lane);
  float a0 = (lane == 0) ? v0.z : 0.0f;
  float a1 = (lane == 0) ? v0.x : 0.0f;
  float a2 = 0.0f, a3 = 0.0f;
  int logScale = 0;

  DECL32(sA)
  DECL32(sB)

  // prime bank A with rows 1..32 (all valid: len >= 500)
  LOAD32(sA, 1)

  int steps = len - 1;               // recurrence covers t = 1 .. len-1
  int mainN = steps & ~63;           // floor to multiple of 64
  int t = 1;
  for (int blk = 0; blk < mainN; blk += 64) {
    // H0: refill bank B (rows t+32..t+63), consume bank A (steps t..t+31)
    LOAD32(sB, t + 32)
    __builtin_amdgcn_sched_barrier(0);
    COMPU32(sA, t)
    // H1: refill bank A (rows t+64..t+95), consume bank B (steps t+32..t+63)
    LOAD32(sA, t + 64)
    __builtin_amdgcn_sched_barrier(0);
    COMPU32(sB, t + 32)
    t += 64;
  }
  {
    // tail: up to 64 guarded steps. Bank A holds rows t..t+31 (loaded by the
    // last H1 or the prime); refill bank B for rows t+32..t+63 (over-reads
    // land in mapped ws; values discarded by the freeze masks).
    LOAD32(sB, t + 32)
    __builtin_amdgcn_sched_barrier(0);
    COMPA32(sA, 0)
    COMPA32(sB, 32)
  }

  __shared__ float fin[256];
  fin[4 * lane + 0] = a0;
  fin[4 * lane + 1] = a1;
  fin[4 * lane + 2] = a2;
  fin[4 * lane + 3] = a3;
  __syncthreads();
  if (lane == 0) {
    int end = 2 * tl;
    float sum = fin[end] + fin[end - 1];
    float loss = -LN2 * (log2f(sum) + (float)logScale);
    atomicAdd(&accum[0], 0.5f * loss);
  }
}

// ---------------- K5: finalize -- KL partial reduction + FP32 output -------
__global__ __launch_bounds__(1024) void finalize_kernel(const float* __restrict__ accum,
                                                        const float* __restrict__ klp,
                                                        float* __restrict__ out) {
  __shared__ float red[16];
  int tid = threadIdx.x;
  float s = 0.0f;
  for (int i = tid; i < 16 * Tlen; i += 1024) s += klp[i];
  s = dppSum64(s);
  int wave = tid >> 6, lane = tid & 63;
  if (lane == 63) red[wave] = s;
  __syncthreads();
  if (tid == 0) {
    float tot = 0.0f;
    #pragma unroll
    for (int w = 0; w < 16; ++w) tot += red[w];
    out[0] = accum[0];
    out[1] = 0.5f * tot;
  }
}

extern "C" void kernel_launch(void* const* d_in, const int* in_sizes, int n_in,
                              void* d_out, int out_size, void* d_ws, size_t ws_size,
                              hipStream_t stream) {
  const float* enc = (const float*)d_in[0];
  const float* W = (const float*)d_in[1];
  const float* bias = (const float*)d_in[2];
  const int* lens = (const int*)d_in[3];
  const int* targets = (const int*)d_in[4];
  const int* tlens = (const int*)d_in[5];

  char* ws = (char*)d_ws;
  u16* a_bf = (u16*)(ws + WS_ABF);
  u16* w_bf = (u16*)(ws + WS_WBF);
  u16* Zb   = (u16*)(ws + WS_Z);
  float* Gp  = (float*)(ws + WS_G);   // aliases a_bf (dead after gemm)
  float* klp = (float*)(ws + WS_KL);  // aliases w_bf (dead after gemm)
  float* accum = (float*)(ws + WS_ACC);

  hipLaunchKernelGGL(convert_kernel, dim3(1024), dim3(256), 0, stream,
                     (const float4*)enc, (const float4*)W, (uint4*)a_bf, (uint4*)w_bf,
                     lens, accum);
  hipLaunchKernelGGL(gemm_kernel, dim3(4000), dim3(256), 0, stream,
                     a_bf, w_bf, lens, Zb);
  hipLaunchKernelGGL(cr_stats_kernel, dim3(16, 1000), dim3(256), 0, stream,
                     Zb, bias, lens, targets, tlens, Gp, klp);
  hipLaunchKernelGGL(ctc_kernel, dim3(Bsz), dim3(64), 0, stream,
                     Gp, targets, lens, tlens, accum);
  hipLaunchKernelGGL(finalize_kernel, dim3(1), dim3(1024), 0, stream,
                     accum, klp, (float*)d_out);
}

// Round 12
// 291.632 us; speedup vs baseline: 1.5178x; 1.5178x over previous
//
#include <hip/hip_runtime.h>
#include <hip/hip_bf16.h>
#include <cstdint>

#define NEG (-1.0e30f)
#define INVLN2 1.44269504088896340736f
#define LN2    0.69314718055994530942f

typedef unsigned short u16;
typedef __attribute__((ext_vector_type(8))) short short8;
typedef __attribute__((ext_vector_type(4))) float f32x4;

typedef const __attribute__((address_space(1))) void cg_void;
typedef __attribute__((address_space(3))) void lds_void;

// dims
#define Bsz   32
#define Tlen  1000
#define Cdim  512
#define Vdim  2000
#define Udim  100
#define Mrows (Bsz * Tlen)   // 32000
#define Npad  2048
#define GROW  256            // G row stride in floats (1024 B)

// ws layout (bytes). G aliases a_bf (dead after gemm); klp aliases w_bf.
#define WS_ABF 0u
#define WS_G   0u
#define WS_WBF 32768000u                    // a_bf/G: 32000*1024
#define WS_KL  WS_WBF                       // 16*1000 floats, aliases w_bf
#define WS_Z   (WS_WBF + 2097152u)          // w_bf: 2048*512*2
#define WS_ACC (WS_Z + 128000000u)          // Z: 32000*2000*2; then accum: 2 floats

__device__ inline u16 f2bf(float x) {
  uint32_t u = __float_as_uint(x);
  uint32_t r = (u + 0x7fffu + ((u >> 16) & 1u)) >> 16;
  return (u16)r;
}
__device__ inline float bf2f(u16 u) {
  return __uint_as_float(((uint32_t)u) << 16);
}

// ---- DPP wave64 reductions (pure VALU, no LDS). Result valid in lane 63. ----
#define DPP_MAX_STAGE(m, ctrl) { \
    int _r = __builtin_amdgcn_update_dpp(__float_as_int(m), __float_as_int(m), \
                                         ctrl, 0xF, 0xF, false); \
    m = fmaxf(m, __int_as_float(_r)); }
#define DPP_SUM_STAGE(v, ctrl) { \
    int _r = __builtin_amdgcn_update_dpp(0, __float_as_int(v), \
                                         ctrl, 0xF, 0xF, true); \
    v += __int_as_float(_r); }

__device__ inline float dppMax64(float m) {
  DPP_MAX_STAGE(m, 0x111) DPP_MAX_STAGE(m, 0x112) DPP_MAX_STAGE(m, 0x114)
  DPP_MAX_STAGE(m, 0x118) DPP_MAX_STAGE(m, 0x142) DPP_MAX_STAGE(m, 0x143)
  return m;  // valid in lane 63
}
__device__ inline float dppSum64(float v) {
  DPP_SUM_STAGE(v, 0x111) DPP_SUM_STAGE(v, 0x112) DPP_SUM_STAGE(v, 0x114)
  DPP_SUM_STAGE(v, 0x118) DPP_SUM_STAGE(v, 0x142) DPP_SUM_STAGE(v, 0x143)
  return v;  // valid in lane 63
}

// shift value from lane-1 into this lane via DPP wave_shr:1 (VALU, no LDS).
__device__ inline float shiftup1(float x, float fill) {
  int r = __builtin_amdgcn_update_dpp(__float_as_int(fill), __float_as_int(x),
                                      0x138, 0xF, 0xF, false);
  return __int_as_float(r);
}

// ---------------- K1: fp32 -> bf16 conversion, vectorized ------------------
__global__ void convert_kernel(const float4* __restrict__ enc4, const float4* __restrict__ W4,
                               uint4* __restrict__ a4, uint4* __restrict__ w4,
                               const int* __restrict__ lens,
                               float* __restrict__ accum) {
  int idx = blockIdx.x * blockDim.x + threadIdx.x;
  int stride = gridDim.x * blockDim.x;
  if (idx == 0) { accum[0] = 0.0f; accum[1] = 0.0f; }
  const int nA = Mrows * Cdim / 8;
  const int nW = Vdim * Cdim / 8;
  const int nWp = Npad * Cdim / 8;
  for (int i = idx; i < nA; i += stride) {
    int row = i >> 6;                 // 64 groups of 8 per 512-col row
    int b = row / 1000;
    int t = row - b * 1000;
    if (t >= lens[b]) continue;       // dead row: Z never read
    float4 x = enc4[2 * i], y = enc4[2 * i + 1];
    uint4 o;
    o.x = (uint32_t)f2bf(x.x) | ((uint32_t)f2bf(x.y) << 16);
    o.y = (uint32_t)f2bf(x.z) | ((uint32_t)f2bf(x.w) << 16);
    o.z = (uint32_t)f2bf(y.x) | ((uint32_t)f2bf(y.y) << 16);
    o.w = (uint32_t)f2bf(y.z) | ((uint32_t)f2bf(y.w) << 16);
    a4[i] = o;
  }
  for (int i = idx; i < nWp; i += stride) {
    uint4 o = {0, 0, 0, 0};
    if (i < nW) {
      float4 x = W4[2 * i], y = W4[2 * i + 1];
      o.x = (uint32_t)f2bf(x.x) | ((uint32_t)f2bf(x.y) << 16);
      o.y = (uint32_t)f2bf(x.z) | ((uint32_t)f2bf(x.w) << 16);
      o.z = (uint32_t)f2bf(y.x) | ((uint32_t)f2bf(y.y) << 16);
      o.w = (uint32_t)f2bf(y.z) | ((uint32_t)f2bf(y.w) << 16);
    }
    w4[i] = o;
  }
}

// ---------------- K2: bf16 GEMM (A: 32000x512, W: 2048x512, C = A*W^T) -----
// Round-12: REVERT to r9's proven 2-phase double-buffer (87 us; the r11
// LDS-free variant regressed to 249 us -- VGPR=76 shows the compiler kept
// only ~1 K-chunk of direct loads in flight, exposing full L2 latency per
// chunk; gload_lds's DMA queue WAS the latency-hiding). Additionally SPLIT
// into two half-M launches (instrumentation: gemm's ~87 us monopolized all
// top-5 dispatch slots, hiding the ~196 us of non-gemm time; halves at ~44
// each let the true ranking of ctc/cr_stats/convert surface in the profile).
// Params: mOff = first mTile of this launch; cFull = # of full 8mx16n
// chunks; a 32-block tail (2 mtiles x 16 n) follows if grid > cFull*128.
__global__ __launch_bounds__(256) void gemm_kernel(const u16* __restrict__ A,
                                                   const u16* __restrict__ Wb,
                                                   const int* __restrict__ lens,
                                                   u16* __restrict__ Z,
                                                   int mOff, int cFull) {
  const int id = blockIdx.x;
  const int c = id >> 7, r = id & 127;
  int mTile, nTile;
  if (c < cFull) { mTile = mOff + c * 8 + (r & 7); nTile = r >> 3; }
  else           { mTile = mOff + cFull * 8 + (r & 1); nTile = r >> 1; }  // 2-mtile tail
  const int mBase = mTile * 128;
  const int nBase = nTile * 128;
  {
    int bSeq = mBase / 1000;
    int t0 = mBase - bSeq * 1000;
    if (t0 <= 872 && t0 >= lens[bSeq]) return;   // whole tile dead
  }

  __shared__ __attribute__((aligned(16))) u16 As[2][128 * 64];   // 2 x 16 KB
  __shared__ __attribute__((aligned(16))) u16 Bs[2][128 * 64];   // 2 x 16 KB
  const int tid = threadIdx.x;
  const int wave = tid >> 6;
  const int lane = tid & 63;
  const int m_lane = lane & 15;
  const int quad = lane >> 4;

  // 8 gload_lds/thread per K-step (A:4, B:4), 16 B each; XOR-swizzled global
  // source + linear LDS dest (both-sides rule), matching swizzled ds_read.
  auto STAGE = [&](int k0, int s) {
    #pragma unroll
    for (int rr = 0; rr < 4; ++rr) {
      int u = rr * 256 + tid;
      int g = u >> 3;
      int q = (u & 7) ^ (g & 7);
      const u16* gpA = A + ((size_t)(mBase + g) << 9) + (k0 + (q << 3));
      __builtin_amdgcn_global_load_lds((cg_void*)gpA, (lds_void*)&As[s][(rr * 4 + wave) * 512],
                                       16, 0, 0);
      const u16* gpB = Wb + ((size_t)(nBase + g) << 9) + (k0 + (q << 3));
      __builtin_amdgcn_global_load_lds((cg_void*)gpB, (lds_void*)&Bs[s][(rr * 4 + wave) * 512],
                                       16, 0, 0);
    }
  };

  f32x4 acc[4][4];
  const f32x4 zero4 = {0.0f, 0.0f, 0.0f, 0.0f};
  #pragma unroll
  for (int i = 0; i < 4; ++i)
    #pragma unroll
    for (int j = 0; j < 4; ++j) acc[i][j] = zero4;

  STAGE(0, 0);
  __syncthreads();                       // drain + barrier: tile 0 ready

  #pragma unroll
  for (int t = 0; t < 8; ++t) {
    const int s = t & 1;
    if (t < 7) STAGE((t + 1) * 64, s ^ 1);   // issue BEFORE compute (hazard-
                                             // free: s^1 readers finished
                                             // before the last barrier)
    #pragma unroll
    for (int kk = 0; kk < 2; ++kk) {
      short8 af[4], bfv[4];
      #pragma unroll
      for (int mi = 0; mi < 4; ++mi) {
        int row = (wave >> 1) * 64 + mi * 16 + m_lane;
        int q = (kk * 4 + quad) ^ (row & 7);
        af[mi] = *(const short8*)&As[s][row * 64 + (q << 3)];
      }
      #pragma unroll
      for (int ni = 0; ni < 4; ++ni) {
        int col = (wave & 1) * 64 + ni * 16 + m_lane;
        int q = (kk * 4 + quad) ^ (col & 7);
        bfv[ni] = *(const short8*)&Bs[s][col * 64 + (q << 3)];
      }
      __builtin_amdgcn_s_setprio(1);
      #pragma unroll
      for (int mi = 0; mi < 4; ++mi)
        #pragma unroll
        for (int ni = 0; ni < 4; ++ni)
          acc[mi][ni] = __builtin_amdgcn_mfma_f32_16x16x32_bf16(af[mi], bfv[ni],
                                                                acc[mi][ni], 0, 0, 0);
      __builtin_amdgcn_s_setprio(0);
    }
    if (t < 7) __syncthreads();          // single drain+barrier per K-step:
                                         // tile t+1 landed; buf s free for t+2
  }

  #pragma unroll
  for (int ni = 0; ni < 4; ++ni) {
    int col = nBase + (wave & 1) * 64 + ni * 16 + m_lane;
    if (col < Vdim) {
      #pragma unroll
      for (int mi = 0; mi < 4; ++mi) {
        int row0 = mBase + (wave >> 1) * 64 + mi * 16 + quad * 4;
        #pragma unroll
        for (int rg = 0; rg < 4; ++rg)
          Z[(size_t)(row0 + rg) * Vdim + col] = f2bf(acc[mi][ni][rg]);
      }
    }
  }
}

// ---------------- K3: fused softmax stats + CR loss + CTC gather -----------
__global__ __launch_bounds__(256) void cr_stats_kernel(const u16* __restrict__ Z,
                                                       const float* __restrict__ bias,
                                                       const int* __restrict__ lens,
                                                       const int* __restrict__ targets,
                                                       const int* __restrict__ tlens,
                                                       float* __restrict__ G,
                                                       float* __restrict__ klp) {
  int bp = blockIdx.x;   // 0..15
  int t = blockIdx.y;    // 0..999
  int tid = threadIdx.x;
  size_t r1 = (size_t)bp * Tlen + t;
  if (t >= lens[bp]) {               // dead block: G rows unread, KL masked
    if (tid == 0) klp[r1] = 0.0f;
    return;
  }
  int wave = tid >> 6, lane = tid & 63;
  size_t r2 = r1 + (size_t)16 * Tlen;
  const u16* z1 = Z + r1 * Vdim;
  const u16* z2 = Z + r2 * Vdim;

  __shared__ __attribute__((aligned(16))) float ls1[Vdim];
  __shared__ __attribute__((aligned(16))) float ls2[Vdim];
  __shared__ float red[8];

  const int c0 = tid * 8;            // this thread's 8 contiguous columns
  float v1[8], v2[8], e1[8], e2[8];
  float mx1 = NEG, mx2 = NEG;
  if (c0 < Vdim) {                   // tid < 250 (2000 = 250*8)
    short8 za = *(const short8*)&z1[c0];
    short8 zb = *(const short8*)&z2[c0];
    float4 b0 = *(const float4*)&bias[c0];
    float4 b1 = *(const float4*)&bias[c0 + 4];
    float bb[8] = {b0.x, b0.y, b0.z, b0.w, b1.x, b1.y, b1.z, b1.w};
    #pragma unroll
    for (int j = 0; j < 8; ++j) {
      v1[j] = bf2f((u16)za[j]) + bb[j];
      v2[j] = bf2f((u16)zb[j]) + bb[j];
      mx1 = fmaxf(mx1, v1[j]);
      mx2 = fmaxf(mx2, v2[j]);
    }
    *(float4*)&ls1[c0]     = (float4){v1[0], v1[1], v1[2], v1[3]};
    *(float4*)&ls1[c0 + 4] = (float4){v1[4], v1[5], v1[6], v1[7]};
    *(float4*)&ls2[c0]     = (float4){v2[0], v2[1], v2[2], v2[3]};
    *(float4*)&ls2[c0 + 4] = (float4){v2[4], v2[5], v2[6], v2[7]};
  } else {
    #pragma unroll
    for (int j = 0; j < 8; ++j) { v1[j] = NEG; v2[j] = NEG; }
  }
  float w1 = dppMax64(mx1), w2 = dppMax64(mx2);
  if (lane == 63) { red[wave] = w1; red[4 + wave] = w2; }
  __syncthreads();
  float M1 = fmaxf(fmaxf(red[0], red[1]), fmaxf(red[2], red[3]));
  float M2 = fmaxf(fmaxf(red[4], red[5]), fmaxf(red[6], red[7]));
  __syncthreads();
  float s1 = 0.0f, s2 = 0.0f;
  #pragma unroll
  for (int j = 0; j < 8; ++j) {
    e1[j] = expf(v1[j] - M1);   // 0 for padded cols (v = NEG)
    e2[j] = expf(v2[j] - M2);
    s1 += e1[j];
    s2 += e2[j];
  }
  s1 = dppSum64(s1); s2 = dppSum64(s2);
  if (lane == 63) { red[wave] = s1; red[4 + wave] = s2; }
  __syncthreads();
  float S1 = red[0] + red[1] + red[2] + red[3];
  float S2 = red[4] + red[5] + red[6] + red[7];
  float c1 = M1 + logf(S1);
  float c2 = M2 + logf(S2);
  float inv1 = 1.0f / S1;
  float inv2 = 1.0f / S2;

  if (tid < 64) {
    int i1 = min(2 * tid, Udim - 1);
    int i3 = min(2 * tid + 1, Udim - 1);
    int t1a = targets[bp * Udim + i1];
    int t1b = targets[bp * Udim + i3];
    int t2a = targets[(bp + 16) * Udim + i1];
    int t2b = targets[(bp + 16) * Udim + i3];
    int tl1 = tlens[bp];
    int tl2 = tlens[bp + 16];
    // LINEAR probabilities; labels past this sequence's target length -> 0
    // (keeps lattice states s > 2*tl exactly 0 in the scan).
    float4 g1 = {(2 * tid < tl1) ? expf(ls1[t1a] - c1) : 0.0f,
                 (2 * tid + 1 < tl1) ? expf(ls1[t1b] - c1) : 0.0f,
                 expf(ls1[0] - c1), 0.0f};
    float4 g2 = {(2 * tid < tl2) ? expf(ls2[t2a] - c2) : 0.0f,
                 (2 * tid + 1 < tl2) ? expf(ls2[t2b] - c2) : 0.0f,
                 expf(ls2[0] - c2), 0.0f};
    *(float4*)(G + r1 * GROW + 4 * tid) = g1;
    *(float4*)(G + r2 * GROW + 4 * tid) = g2;
  }

  float f = 0.0f;
  #pragma unroll
  for (int j = 0; j < 8; ++j) {
    // p = expf(v - c) == e * (1/S), exactly; padded cols: (0-0)*(NEG-NEG)=0.
    float p1 = e1[j] * inv1;
    float p2 = e2[j] * inv2;
    f += (p1 - p2) * (v1[j] - v2[j]);
  }
  __syncthreads();
  f = dppSum64(f);
  if (lane == 63) red[wave] = f;
  __syncthreads();
  if (tid == 0) {
    klp[r1] = red[0] + red[1] + red[2] + red[3];  // plain store, no atomic
  }
}

// ---------------- K4: CTC forward scan, one wave per sequence --------------
#define DECL3(p, i) float p##i##x, p##i##y, p##i##b;
#define LOADR(p, i, row) { float4 v = *(const float4*)(gb + (size_t)(row) * GROW + 4 * lane); \
    p##i##x = v.x; p##i##y = v.y; p##i##b = v.z; }

// unconditional step (main loop: every step here satisfies t < len)
#define COMPU(p, i) { \
    float pX = p##i##x, pY = p##i##y, pB = p##i##b; \
    float p3 = shiftup1(a3, 0.0f); \
    float t01 = a1 + a0; \
    float t23 = a3 + a2; \
    float n0 = (a0 + p3) * pB; \
    float n1 = fmaf(p3, fm1, t01) * pX; \
    float n2 = (a2 + a1) * pB; \
    float n3 = fmaf(a1, fm3, t23) * pY; \
    a0 = n0; a1 = n1; a2 = n2; a3 = n3; }

// guarded step (tail: freeze once past this sequence's input length)
#define COMPA(p, i, off) { \
    float pX = p##i##x, pY = p##i##y, pB = p##i##b; \
    float p3 = shiftup1(a3, 0.0f); \
    float t01 = a1 + a0; \
    float t23 = a3 + a2; \
    float n0 = (a0 + p3) * pB; \
    float n1 = fmaf(p3, fm1, t01) * pX; \
    float n2 = (a2 + a1) * pB; \
    float n3 = fmaf(a1, fm3, t23) * pY; \
    bool act = (t + (off)) < len; \
    a0 = act ? n0 : a0; a1 = act ? n1 : a1; \
    a2 = act ? n2 : a2; a3 = act ? n3 : a3; }

// DPP wave-max step: bound_ctrl=true fills invalid lanes with 0 (all a >= 0)
#define DPPMAX(m, ctrl) { int _r = __builtin_amdgcn_update_dpp(0,              \
      __float_as_int(m), ctrl, 0xF, 0xF, true);                               \
    m = fmaxf(m, __int_as_float(_r)); }

// Exact kill of states that cannot reach the readout, then exact power-of-2
// rescale pinning the wave max at ~2^100; logScale tracks the total scale.
#define RESCALE_KILL(tdone) {                                                 \
    int R = len - 1 - (tdone); R = R < 0 ? 0 : R;                             \
    int lo = end1 - 2 * R;                                                    \
    a0 = (base4 + 0 >= lo) ? a0 : 0.0f;                                       \
    a1 = (base4 + 1 >= lo) ? a1 : 0.0f;                                       \
    a2 = (base4 + 2 >= lo) ? a2 : 0.0f;                                       \
    a3 = (base4 + 3 >= lo) ? a3 : 0.0f;                                       \
    float m = fmaxf(fmaxf(a0, a1), fmaxf(a2, a3));                            \
    DPPMAX(m, 0x111) DPPMAX(m, 0x112) DPPMAX(m, 0x114) DPPMAX(m, 0x118)       \
    DPPMAX(m, 0x142) DPPMAX(m, 0x143)                                         \
    uint32_t mb = (uint32_t)__builtin_amdgcn_readlane(__float_as_int(m), 63); \
    int e = (int)((mb >> 23) & 0xffu);                                        \
    int sh = 227 - e;                                                         \
    sh = sh > 127 ? 127 : (sh < -126 ? -126 : sh);                            \
    float sc = __uint_as_float((uint32_t)(sh + 127) << 23);                   \
    a0 *= sc; a1 *= sc; a2 *= sc; a3 *= sc;                                   \
    logScale -= sh; }

#define LOAD32(p, base) \
    LOADR(p, 0,  (base) + 0)  LOADR(p, 1,  (base) + 1)  LOADR(p, 2,  (base) + 2)  LOADR(p, 3,  (base) + 3)  \
    LOADR(p, 4,  (base) + 4)  LOADR(p, 5,  (base) + 5)  LOADR(p, 6,  (base) + 6)  LOADR(p, 7,  (base) + 7)  \
    LOADR(p, 8,  (base) + 8)  LOADR(p, 9,  (base) + 9)  LOADR(p, 10, (base) + 10) LOADR(p, 11, (base) + 11) \
    LOADR(p, 12, (base) + 12) LOADR(p, 13, (base) + 13) LOADR(p, 14, (base) + 14) LOADR(p, 15, (base) + 15) \
    LOADR(p, 16, (base) + 16) LOADR(p, 17, (base) + 17) LOADR(p, 18, (base) + 18) LOADR(p, 19, (base) + 19) \
    LOADR(p, 20, (base) + 20) LOADR(p, 21, (base) + 21) LOADR(p, 22, (base) + 22) LOADR(p, 23, (base) + 23) \
    LOADR(p, 24, (base) + 24) LOADR(p, 25, (base) + 25) LOADR(p, 26, (base) + 26) LOADR(p, 27, (base) + 27) \
    LOADR(p, 28, (base) + 28) LOADR(p, 29, (base) + 29) LOADR(p, 30, (base) + 30) LOADR(p, 31, (base) + 31)

#define COMPU32(p, tb) \
    COMPU(p, 0)  COMPU(p, 1)  COMPU(p, 2)  COMPU(p, 3)  \
    COMPU(p, 4)  COMPU(p, 5)  COMPU(p, 6)  COMPU(p, 7)  \
    RESCALE_KILL((tb) + 7) \
    COMPU(p, 8)  COMPU(p, 9)  COMPU(p, 10) COMPU(p, 11) \
    COMPU(p, 12) COMPU(p, 13) COMPU(p, 14) COMPU(p, 15) \
    RESCALE_KILL((tb) + 15) \
    COMPU(p, 16) COMPU(p, 17) COMPU(p, 18) COMPU(p, 19) \
    COMPU(p, 20) COMPU(p, 21) COMPU(p, 22) COMPU(p, 23) \
    RESCALE_KILL((tb) + 23) \
    COMPU(p, 24) COMPU(p, 25) COMPU(p, 26) COMPU(p, 27) \
    COMPU(p, 28) COMPU(p, 29) COMPU(p, 30) COMPU(p, 31) \
    RESCALE_KILL((tb) + 31)

#define COMPA32(p, o) \
    COMPA(p, 0,  (o) + 0)  COMPA(p, 1,  (o) + 1)  COMPA(p, 2,  (o) + 2)  COMPA(p, 3,  (o) + 3)  \
    COMPA(p, 4,  (o) + 4)  COMPA(p, 5,  (o) + 5)  COMPA(p, 6,  (o) + 6)  COMPA(p, 7,  (o) + 7)  \
    RESCALE_KILL(t + (o) + 7) \
    COMPA(p, 8,  (o) + 8)  COMPA(p, 9,  (o) + 9)  COMPA(p, 10, (o) + 10) COMPA(p, 11, (o) + 11) \
    COMPA(p, 12, (o) + 12) COMPA(p, 13, (o) + 13) COMPA(p, 14, (o) + 14) COMPA(p, 15, (o) + 15) \
    RESCALE_KILL(t + (o) + 15) \
    COMPA(p, 16, (o) + 16) COMPA(p, 17, (o) + 17) COMPA(p, 18, (o) + 18) COMPA(p, 19, (o) + 19) \
    COMPA(p, 20, (o) + 20) COMPA(p, 21, (o) + 21) COMPA(p, 22, (o) + 22) COMPA(p, 23, (o) + 23) \
    RESCALE_KILL(t + (o) + 23) \
    COMPA(p, 24, (o) + 24) COMPA(p, 25, (o) + 25) COMPA(p, 26, (o) + 26) COMPA(p, 27, (o) + 27) \
    COMPA(p, 28, (o) + 28) COMPA(p, 29, (o) + 29) COMPA(p, 30, (o) + 30) COMPA(p, 31, (o) + 31) \
    RESCALE_KILL(t + (o) + 31)

#define DECL32(p) \
    DECL3(p, 0)  DECL3(p, 1)  DECL3(p, 2)  DECL3(p, 3)  DECL3(p, 4)  DECL3(p, 5)  DECL3(p, 6)  DECL3(p, 7)  \
    DECL3(p, 8)  DECL3(p, 9)  DECL3(p, 10) DECL3(p, 11) DECL3(p, 12) DECL3(p, 13) DECL3(p, 14) DECL3(p, 15) \
    DECL3(p, 16) DECL3(p, 17) DECL3(p, 18) DECL3(p, 19) DECL3(p, 20) DECL3(p, 21) DECL3(p, 22) DECL3(p, 23) \
    DECL3(p, 24) DECL3(p, 25) DECL3(p, 26) DECL3(p, 27) DECL3(p, 28) DECL3(p, 29) DECL3(p, 30) DECL3(p, 31)

__global__ __launch_bounds__(64, 1) void ctc_kernel(const float* __restrict__ G,
                                                    const int* __restrict__ targets,
                                                    const int* __restrict__ lens,
                                                    const int* __restrict__ tlens,
                                                    float* __restrict__ accum) {
  int b = blockIdx.x;
  int lane = threadIdx.x;
  const int* tgt = targets + b * Udim;
  int i1 = min(2 * lane, Udim - 1);
  int i3 = min(2 * lane + 1, Udim - 1);
  int l1 = tgt[i1];
  int l3 = tgt[i3];
  int lm1 = tgt[min(max(2 * lane - 1, 0), Udim - 1)];
  const float fm1 = ((lane >= 1) && (l1 != lm1)) ? 1.0f : 0.0f;  // skip1 mask
  const float fm3 = (l3 != l1) ? 1.0f : 0.0f;                    // skip3 mask
  int len = lens[b];
  int tl = tlens[b];
  const int end1 = 2 * tl - 1;       // readout states are end1 and end1+1
  const int base4 = 4 * lane;        // this lane owns states base4..base4+3
  const float* gb = G + (size_t)b * Tlen * GROW;

  // t=0 init (linear space): lane0's float4 = {p(tgt0), p(tgt1), blank, 0}
  float4 v0 = *(const float4*)(gb + 4 * lane);
  float a0 = (lane == 0) ? v0.z : 0.0f;
  float a1 = (lane == 0) ? v0.x : 0.0f;
  float a2 = 0.0f, a3 = 0.0f;
  int logScale = 0;

  DECL32(sA)
  DECL32(sB)

  // prime bank A with rows 1..32 (all valid: len >= 500)
  LOAD32(sA, 1)

  int steps = len - 1;               // recurrence covers t = 1 .. len-1
  int mainN = steps & ~63;           // floor to multiple of 64
  int t = 1;
  for (int blk = 0; blk < mainN; blk += 64) {
    // H0: refill bank B (rows t+32..t+63), consume bank A (steps t..t+31)
    LOAD32(sB, t + 32)
    __builtin_amdgcn_sched_barrier(0);
    COMPU32(sA, t)
    // H1: refill bank A (rows t+64..t+95), consume bank B (steps t+32..t+63)
    LOAD32(sA, t + 64)
    __builtin_amdgcn_sched_barrier(0);
    COMPU32(sB, t + 32)
    t += 64;
  }
  {
    // tail: up to 64 guarded steps. Bank A holds rows t..t+31 (loaded by the
    // last H1 or the prime); refill bank B for rows t+32..t+63 (over-reads
    // land in mapped ws; values discarded by the freeze masks).
    LOAD32(sB, t + 32)
    __builtin_amdgcn_sched_barrier(0);
    COMPA32(sA, 0)
    COMPA32(sB, 32)
  }

  __shared__ float fin[256];
  fin[4 * lane + 0] = a0;
  fin[4 * lane + 1] = a1;
  fin[4 * lane + 2] = a2;
  fin[4 * lane + 3] = a3;
  __syncthreads();
  if (lane == 0) {
    int end = 2 * tl;
    float sum = fin[end] + fin[end - 1];
    float loss = -LN2 * (log2f(sum) + (float)logScale);
    atomicAdd(&accum[0], 0.5f * loss);
  }
}

// ---------------- K5: finalize -- KL partial reduction + FP32 output -------
__global__ __launch_bounds__(1024) void finalize_kernel(const float* __restrict__ accum,
                                                        const float* __restrict__ klp,
                                                        float* __restrict__ out) {
  __shared__ float red[16];
  int tid = threadIdx.x;
  float s = 0.0f;
  for (int i = tid; i < 16 * Tlen; i += 1024) s += klp[i];
  s = dppSum64(s);
  int wave = tid >> 6, lane = tid & 63;
  if (lane == 63) red[wave] = s;
  __syncthreads();
  if (tid == 0) {
    float tot = 0.0f;
    #pragma unroll
    for (int w = 0; w < 16; ++w) tot += red[w];
    out[0] = accum[0];
    out[1] = 0.5f * tot;
  }
}

extern "C" void kernel_launch(void* const* d_in, const int* in_sizes, int n_in,
                              void* d_out, int out_size, void* d_ws, size_t ws_size,
                              hipStream_t stream) {
  const float* enc = (const float*)d_in[0];
  const float* W = (const float*)d_in[1];
  const float* bias = (const float*)d_in[2];
  const int* lens = (const int*)d_in[3];
  const int* targets = (const int*)d_in[4];
  const int* tlens = (const int*)d_in[5];

  char* ws = (char*)d_ws;
  u16* a_bf = (u16*)(ws + WS_ABF);
  u16* w_bf = (u16*)(ws + WS_WBF);
  u16* Zb   = (u16*)(ws + WS_Z);
  float* Gp  = (float*)(ws + WS_G);   // aliases a_bf (dead after gemm)
  float* klp = (float*)(ws + WS_KL);  // aliases w_bf (dead after gemm)
  float* accum = (float*)(ws + WS_ACC);

  hipLaunchKernelGGL(convert_kernel, dim3(1024), dim3(256), 0, stream,
                     (const float4*)enc, (const float4*)W, (uint4*)a_bf, (uint4*)w_bf,
                     lens, accum);
  // gemm split into two half-M launches (instrumentation; see K2 comment):
  // launch 1: mTiles 0..127   (16 full chunks, no tail)  -> 2048 blocks
  // launch 2: mTiles 128..249 (15 full chunks + 2-mtile tail) -> 1952 blocks
  hipLaunchKernelGGL(gemm_kernel, dim3(2048), dim3(256), 0, stream,
                     a_bf, w_bf, lens, Zb, 0, 16);
  hipLaunchKernelGGL(gemm_kernel, dim3(1952), dim3(256), 0, stream,
                     a_bf, w_bf, lens, Zb, 128, 15);
  hipLaunchKernelGGL(cr_stats_kernel, dim3(16, 1000), dim3(256), 0, stream,
                     Zb, bias, lens, targets, tlens, Gp, klp);
  hipLaunchKernelGGL(ctc_kernel, dim3(Bsz), dim3(64), 0, stream,
                     Gp, targets, lens, tlens, accum);
  hipLaunchKernelGGL(finalize_kernel, dim3(1), dim3(1024), 0, stream,
                     accum, klp, (float*)d_out);
}

// Round 13
// 274.428 us; speedup vs baseline: 1.6130x; 1.0627x over previous
//
#include <hip/hip_runtime.h>
#include <hip/hip_bf16.h>
#include <cstdint>

#define NEG (-1.0e30f)
#define INVLN2 1.44269504088896340736f
#define LN2    0.69314718055994530942f

typedef unsigned short u16;
typedef __attribute__((ext_vector_type(8))) short short8;
typedef __attribute__((ext_vector_type(4))) float f32x4;
typedef __attribute__((ext_vector_type(3))) float f32x3;

typedef const __attribute__((address_space(1))) void cg_void;
typedef __attribute__((address_space(3))) void lds_void;

// dims
#define Bsz   32
#define Tlen  1000
#define Cdim  512
#define Vdim  2000
#define Udim  100
#define Mrows (Bsz * Tlen)   // 32000
#define Npad  2048
#define GROW  256            // G row stride in floats (1024 B)

// ws layout (bytes). G aliases a_bf (dead after gemm); klp aliases w_bf.
#define WS_ABF 0u
#define WS_G   0u
#define WS_WBF 32768000u                    // a_bf/G: 32000*1024
#define WS_KL  WS_WBF                       // 16*1000 floats, aliases w_bf
#define WS_Z   (WS_WBF + 2097152u)          // w_bf: 2048*512*2
#define WS_ACC (WS_Z + 128000000u)          // Z: 32000*2000*2; then accum: 2 floats

__device__ inline u16 f2bf(float x) {
  uint32_t u = __float_as_uint(x);
  uint32_t r = (u + 0x7fffu + ((u >> 16) & 1u)) >> 16;
  return (u16)r;
}
__device__ inline float bf2f(u16 u) {
  return __uint_as_float(((uint32_t)u) << 16);
}

// ---- DPP wave64 reductions (pure VALU, no LDS). Result valid in lane 63. ----
#define DPP_MAX_STAGE(m, ctrl) { \
    int _r = __builtin_amdgcn_update_dpp(__float_as_int(m), __float_as_int(m), \
                                         ctrl, 0xF, 0xF, false); \
    m = fmaxf(m, __int_as_float(_r)); }
#define DPP_SUM_STAGE(v, ctrl) { \
    int _r = __builtin_amdgcn_update_dpp(0, __float_as_int(v), \
                                         ctrl, 0xF, 0xF, true); \
    v += __int_as_float(_r); }

__device__ inline float dppMax64(float m) {
  DPP_MAX_STAGE(m, 0x111) DPP_MAX_STAGE(m, 0x112) DPP_MAX_STAGE(m, 0x114)
  DPP_MAX_STAGE(m, 0x118) DPP_MAX_STAGE(m, 0x142) DPP_MAX_STAGE(m, 0x143)
  return m;  // valid in lane 63
}
__device__ inline float dppSum64(float v) {
  DPP_SUM_STAGE(v, 0x111) DPP_SUM_STAGE(v, 0x112) DPP_SUM_STAGE(v, 0x114)
  DPP_SUM_STAGE(v, 0x118) DPP_SUM_STAGE(v, 0x142) DPP_SUM_STAGE(v, 0x143)
  return v;  // valid in lane 63
}

// shift value from lane-1 into this lane via DPP wave_shr:1 (VALU, no LDS).
__device__ inline float shiftup1(float x, float fill) {
  int r = __builtin_amdgcn_update_dpp(__float_as_int(fill), __float_as_int(x),
                                      0x138, 0xF, 0xF, false);
  return __int_as_float(r);
}

// ---------------- K1: fp32 -> bf16 conversion, vectorized ------------------
__global__ void convert_kernel(const float4* __restrict__ enc4, const float4* __restrict__ W4,
                               uint4* __restrict__ a4, uint4* __restrict__ w4,
                               const int* __restrict__ lens,
                               float* __restrict__ accum) {
  int idx = blockIdx.x * blockDim.x + threadIdx.x;
  int stride = gridDim.x * blockDim.x;
  if (idx == 0) { accum[0] = 0.0f; accum[1] = 0.0f; }
  const int nA = Mrows * Cdim / 8;
  const int nW = Vdim * Cdim / 8;
  const int nWp = Npad * Cdim / 8;
  for (int i = idx; i < nA; i += stride) {
    int row = i >> 6;                 // 64 groups of 8 per 512-col row
    int b = row / 1000;
    int t = row - b * 1000;
    if (t >= lens[b]) continue;       // dead row: Z never read
    float4 x = enc4[2 * i], y = enc4[2 * i + 1];
    uint4 o;
    o.x = (uint32_t)f2bf(x.x) | ((uint32_t)f2bf(x.y) << 16);
    o.y = (uint32_t)f2bf(x.z) | ((uint32_t)f2bf(x.w) << 16);
    o.z = (uint32_t)f2bf(y.x) | ((uint32_t)f2bf(y.y) << 16);
    o.w = (uint32_t)f2bf(y.z) | ((uint32_t)f2bf(y.w) << 16);
    a4[i] = o;
  }
  for (int i = idx; i < nWp; i += stride) {
    uint4 o = {0, 0, 0, 0};
    if (i < nW) {
      float4 x = W4[2 * i], y = W4[2 * i + 1];
      o.x = (uint32_t)f2bf(x.x) | ((uint32_t)f2bf(x.y) << 16);
      o.y = (uint32_t)f2bf(x.z) | ((uint32_t)f2bf(x.w) << 16);
      o.z = (uint32_t)f2bf(y.x) | ((uint32_t)f2bf(y.y) << 16);
      o.w = (uint32_t)f2bf(y.z) | ((uint32_t)f2bf(y.w) << 16);
    }
    w4[i] = o;
  }
}

// ---------------- K2: bf16 GEMM (A: 32000x512, W: 2048x512, C = A*W^T) -----
// r9's proven 2-phase double-buffer, single launch (r12's half-M split was
// instrumentation only and cost ~8 us serialization; ranking obtained).
__global__ __launch_bounds__(256) void gemm_kernel(const u16* __restrict__ A,
                                                   const u16* __restrict__ Wb,
                                                   const int* __restrict__ lens,
                                                   u16* __restrict__ Z) {
  const int id = blockIdx.x;
  const int c = id >> 7, r = id & 127;
  int mTile, nTile;
  if (c < 31) { mTile = c * 8 + (r & 7); nTile = r >> 3; }
  else        { mTile = 248 + (r & 1);   nTile = r >> 1; }   // tail ids 3968..3999
  const int mBase = mTile * 128;
  const int nBase = nTile * 128;
  {
    int bSeq = mBase / 1000;
    int t0 = mBase - bSeq * 1000;
    if (t0 <= 872 && t0 >= lens[bSeq]) return;   // whole tile dead
  }

  __shared__ __attribute__((aligned(16))) u16 As[2][128 * 64];   // 2 x 16 KB
  __shared__ __attribute__((aligned(16))) u16 Bs[2][128 * 64];   // 2 x 16 KB
  const int tid = threadIdx.x;
  const int wave = tid >> 6;
  const int lane = tid & 63;
  const int m_lane = lane & 15;
  const int quad = lane >> 4;

  // 8 gload_lds/thread per K-step (A:4, B:4), 16 B each; XOR-swizzled global
  // source + linear LDS dest (both-sides rule), matching swizzled ds_read.
  auto STAGE = [&](int k0, int s) {
    #pragma unroll
    for (int rr = 0; rr < 4; ++rr) {
      int u = rr * 256 + tid;
      int g = u >> 3;
      int q = (u & 7) ^ (g & 7);
      const u16* gpA = A + ((size_t)(mBase + g) << 9) + (k0 + (q << 3));
      __builtin_amdgcn_global_load_lds((cg_void*)gpA, (lds_void*)&As[s][(rr * 4 + wave) * 512],
                                       16, 0, 0);
      const u16* gpB = Wb + ((size_t)(nBase + g) << 9) + (k0 + (q << 3));
      __builtin_amdgcn_global_load_lds((cg_void*)gpB, (lds_void*)&Bs[s][(rr * 4 + wave) * 512],
                                       16, 0, 0);
    }
  };

  f32x4 acc[4][4];
  const f32x4 zero4 = {0.0f, 0.0f, 0.0f, 0.0f};
  #pragma unroll
  for (int i = 0; i < 4; ++i)
    #pragma unroll
    for (int j = 0; j < 4; ++j) acc[i][j] = zero4;

  STAGE(0, 0);
  __syncthreads();                       // drain + barrier: tile 0 ready

  #pragma unroll
  for (int t = 0; t < 8; ++t) {
    const int s = t & 1;
    if (t < 7) STAGE((t + 1) * 64, s ^ 1);   // issue BEFORE compute (hazard-
                                             // free: s^1 readers finished
                                             // before the last barrier)
    #pragma unroll
    for (int kk = 0; kk < 2; ++kk) {
      short8 af[4], bfv[4];
      #pragma unroll
      for (int mi = 0; mi < 4; ++mi) {
        int row = (wave >> 1) * 64 + mi * 16 + m_lane;
        int q = (kk * 4 + quad) ^ (row & 7);
        af[mi] = *(const short8*)&As[s][row * 64 + (q << 3)];
      }
      #pragma unroll
      for (int ni = 0; ni < 4; ++ni) {
        int col = (wave & 1) * 64 + ni * 16 + m_lane;
        int q = (kk * 4 + quad) ^ (col & 7);
        bfv[ni] = *(const short8*)&Bs[s][col * 64 + (q << 3)];
      }
      __builtin_amdgcn_s_setprio(1);
      #pragma unroll
      for (int mi = 0; mi < 4; ++mi)
        #pragma unroll
        for (int ni = 0; ni < 4; ++ni)
          acc[mi][ni] = __builtin_amdgcn_mfma_f32_16x16x32_bf16(af[mi], bfv[ni],
                                                                acc[mi][ni], 0, 0, 0);
      __builtin_amdgcn_s_setprio(0);
    }
    if (t < 7) __syncthreads();          // single drain+barrier per K-step:
                                         // tile t+1 landed; buf s free for t+2
  }

  #pragma unroll
  for (int ni = 0; ni < 4; ++ni) {
    int col = nBase + (wave & 1) * 64 + ni * 16 + m_lane;
    if (col < Vdim) {
      #pragma unroll
      for (int mi = 0; mi < 4; ++mi) {
        int row0 = mBase + (wave >> 1) * 64 + mi * 16 + quad * 4;
        #pragma unroll
        for (int rg = 0; rg < 4; ++rg)
          Z[(size_t)(row0 + rg) * Vdim + col] = f2bf(acc[mi][ni][rg]);
      }
    }
  }
}

// ---------------- K3: fused softmax stats + CR loss + CTC gather -----------
__global__ __launch_bounds__(256) void cr_stats_kernel(const u16* __restrict__ Z,
                                                       const float* __restrict__ bias,
                                                       const int* __restrict__ lens,
                                                       const int* __restrict__ targets,
                                                       const int* __restrict__ tlens,
                                                       float* __restrict__ G,
                                                       float* __restrict__ klp) {
  int bp = blockIdx.x;   // 0..15
  int t = blockIdx.y;    // 0..999
  int tid = threadIdx.x;
  size_t r1 = (size_t)bp * Tlen + t;
  if (t >= lens[bp]) {               // dead block: G rows unread, KL masked
    if (tid == 0) klp[r1] = 0.0f;
    return;
  }
  int wave = tid >> 6, lane = tid & 63;
  size_t r2 = r1 + (size_t)16 * Tlen;
  const u16* z1 = Z + r1 * Vdim;
  const u16* z2 = Z + r2 * Vdim;

  __shared__ __attribute__((aligned(16))) float ls1[Vdim];
  __shared__ __attribute__((aligned(16))) float ls2[Vdim];
  __shared__ float red[8];

  const int c0 = tid * 8;            // this thread's 8 contiguous columns
  float v1[8], v2[8], e1[8], e2[8];
  float mx1 = NEG, mx2 = NEG;
  if (c0 < Vdim) {                   // tid < 250 (2000 = 250*8)
    short8 za = *(const short8*)&z1[c0];
    short8 zb = *(const short8*)&z2[c0];
    float4 b0 = *(const float4*)&bias[c0];
    float4 b1 = *(const float4*)&bias[c0 + 4];
    float bb[8] = {b0.x, b0.y, b0.z, b0.w, b1.x, b1.y, b1.z, b1.w};
    #pragma unroll
    for (int j = 0; j < 8; ++j) {
      v1[j] = bf2f((u16)za[j]) + bb[j];
      v2[j] = bf2f((u16)zb[j]) + bb[j];
      mx1 = fmaxf(mx1, v1[j]);
      mx2 = fmaxf(mx2, v2[j]);
    }
    *(float4*)&ls1[c0]     = (float4){v1[0], v1[1], v1[2], v1[3]};
    *(float4*)&ls1[c0 + 4] = (float4){v1[4], v1[5], v1[6], v1[7]};
    *(float4*)&ls2[c0]     = (float4){v2[0], v2[1], v2[2], v2[3]};
    *(float4*)&ls2[c0 + 4] = (float4){v2[4], v2[5], v2[6], v2[7]};
  } else {
    #pragma unroll
    for (int j = 0; j < 8; ++j) { v1[j] = NEG; v2[j] = NEG; }
  }
  float w1 = dppMax64(mx1), w2 = dppMax64(mx2);
  if (lane == 63) { red[wave] = w1; red[4 + wave] = w2; }
  __syncthreads();
  float M1 = fmaxf(fmaxf(red[0], red[1]), fmaxf(red[2], red[3]));
  float M2 = fmaxf(fmaxf(red[4], red[5]), fmaxf(red[6], red[7]));
  __syncthreads();
  float s1 = 0.0f, s2 = 0.0f;
  #pragma unroll
  for (int j = 0; j < 8; ++j) {
    e1[j] = expf(v1[j] - M1);   // 0 for padded cols (v = NEG)
    e2[j] = expf(v2[j] - M2);
    s1 += e1[j];
    s2 += e2[j];
  }
  s1 = dppSum64(s1); s2 = dppSum64(s2);
  if (lane == 63) { red[wave] = s1; red[4 + wave] = s2; }
  __syncthreads();
  float S1 = red[0] + red[1] + red[2] + red[3];
  float S2 = red[4] + red[5] + red[6] + red[7];
  float c1 = M1 + logf(S1);
  float c2 = M2 + logf(S2);
  float inv1 = 1.0f / S1;
  float inv2 = 1.0f / S2;

  if (tid < 64) {
    int i1 = min(2 * tid, Udim - 1);
    int i3 = min(2 * tid + 1, Udim - 1);
    int t1a = targets[bp * Udim + i1];
    int t1b = targets[bp * Udim + i3];
    int t2a = targets[(bp + 16) * Udim + i1];
    int t2b = targets[(bp + 16) * Udim + i3];
    int tl1 = tlens[bp];
    int tl2 = tlens[bp + 16];
    // LINEAR probabilities; labels past this sequence's target length -> 0
    // (keeps lattice states s > 2*tl exactly 0 in the scan).
    float4 g1 = {(2 * tid < tl1) ? expf(ls1[t1a] - c1) : 0.0f,
                 (2 * tid + 1 < tl1) ? expf(ls1[t1b] - c1) : 0.0f,
                 expf(ls1[0] - c1), 0.0f};
    float4 g2 = {(2 * tid < tl2) ? expf(ls2[t2a] - c2) : 0.0f,
                 (2 * tid + 1 < tl2) ? expf(ls2[t2b] - c2) : 0.0f,
                 expf(ls2[0] - c2), 0.0f};
    *(float4*)(G + r1 * GROW + 4 * tid) = g1;
    *(float4*)(G + r2 * GROW + 4 * tid) = g2;
  }

  float f = 0.0f;
  #pragma unroll
  for (int j = 0; j < 8; ++j) {
    // p = expf(v - c) == e * (1/S), exactly; padded cols: (0-0)*(NEG-NEG)=0.
    float p1 = e1[j] * inv1;
    float p2 = e2[j] * inv2;
    f += (p1 - p2) * (v1[j] - v2[j]);
  }
  __syncthreads();
  f = dppSum64(f);
  if (lane == 63) red[wave] = f;
  __syncthreads();
  if (tid == 0) {
    klp[r1] = red[0] + red[1] + red[2] + red[3];  // plain store, no atomic
  }
}

// ---------------- K4: CTC forward scan, one wave per sequence --------------
// Round-13: loads land DIRECTLY in bank registers. r12 counters (VGPR=148,
// VALUBusy 1.1%, 134 cyc/step vs ~30 modeled) showed the float4 LOAD32
// batch needs 128 transient dest VGPRs it doesn't have -> compiler split
// the batch with mid-batch waitcnt+copies, exposing ~4 HBM latency windows
// per 32 steps. Fix: f32x3 loads (global_load_dwordx3) whose dest IS the
// persistent bank triple -- zero copies, zero transient regs; all 32 loads
// issue back-to-back; one (covered) wait per bank swap. VGPR ~210-230,
// still 1 wave/SIMD, no spill.
#define DECL3(p, i) float p##i##x, p##i##y, p##i##b;
#define LOADR(p, i, row) { f32x3 v = *(const f32x3*)(gb + (size_t)(row) * GROW + 4 * lane); \
    p##i##x = v.x; p##i##y = v.y; p##i##b = v.z; }

// unconditional step (main loop: every step here satisfies t < len)
#define COMPU(p, i) { \
    float pX = p##i##x, pY = p##i##y, pB = p##i##b; \
    float p3 = shiftup1(a3, 0.0f); \
    float t01 = a1 + a0; \
    float t23 = a3 + a2; \
    float n0 = (a0 + p3) * pB; \
    float n1 = fmaf(p3, fm1, t01) * pX; \
    float n2 = (a2 + a1) * pB; \
    float n3 = fmaf(a1, fm3, t23) * pY; \
    a0 = n0; a1 = n1; a2 = n2; a3 = n3; }

// guarded step (tail: freeze once past this sequence's input length)
#define COMPA(p, i, off) { \
    float pX = p##i##x, pY = p##i##y, pB = p##i##b; \
    float p3 = shiftup1(a3, 0.0f); \
    float t01 = a1 + a0; \
    float t23 = a3 + a2; \
    float n0 = (a0 + p3) * pB; \
    float n1 = fmaf(p3, fm1, t01) * pX; \
    float n2 = (a2 + a1) * pB; \
    float n3 = fmaf(a1, fm3, t23) * pY; \
    bool act = (t + (off)) < len; \
    a0 = act ? n0 : a0; a1 = act ? n1 : a1; \
    a2 = act ? n2 : a2; a3 = act ? n3 : a3; }

// DPP wave-max step: bound_ctrl=true fills invalid lanes with 0 (all a >= 0)
#define DPPMAX(m, ctrl) { int _r = __builtin_amdgcn_update_dpp(0,              \
      __float_as_int(m), ctrl, 0xF, 0xF, true);                               \
    m = fmaxf(m, __int_as_float(_r)); }

// Exact kill of states that cannot reach the readout, then exact power-of-2
// rescale pinning the wave max at ~2^100; logScale tracks the total scale.
#define RESCALE_KILL(tdone) {                                                 \
    int R = len - 1 - (tdone); R = R < 0 ? 0 : R;                             \
    int lo = end1 - 2 * R;                                                    \
    a0 = (base4 + 0 >= lo) ? a0 : 0.0f;                                       \
    a1 = (base4 + 1 >= lo) ? a1 : 0.0f;                                       \
    a2 = (base4 + 2 >= lo) ? a2 : 0.0f;                                       \
    a3 = (base4 + 3 >= lo) ? a3 : 0.0f;                                       \
    float m = fmaxf(fmaxf(a0, a1), fmaxf(a2, a3));                            \
    DPPMAX(m, 0x111) DPPMAX(m, 0x112) DPPMAX(m, 0x114) DPPMAX(m, 0x118)       \
    DPPMAX(m, 0x142) DPPMAX(m, 0x143)                                         \
    uint32_t mb = (uint32_t)__builtin_amdgcn_readlane(__float_as_int(m), 63); \
    int e = (int)((mb >> 23) & 0xffu);                                        \
    int sh = 227 - e;                                                         \
    sh = sh > 127 ? 127 : (sh < -126 ? -126 : sh);                            \
    float sc = __uint_as_float((uint32_t)(sh + 127) << 23);                   \
    a0 *= sc; a1 *= sc; a2 *= sc; a3 *= sc;                                   \
    logScale -= sh; }

#define LOAD32(p, base) \
    LOADR(p, 0,  (base) + 0)  LOADR(p, 1,  (base) + 1)  LOADR(p, 2,  (base) + 2)  LOADR(p, 3,  (base) + 3)  \
    LOADR(p, 4,  (base) + 4)  LOADR(p, 5,  (base) + 5)  LOADR(p, 6,  (base) + 6)  LOADR(p, 7,  (base) + 7)  \
    LOADR(p, 8,  (base) + 8)  LOADR(p, 9,  (base) + 9)  LOADR(p, 10, (base) + 10) LOADR(p, 11, (base) + 11) \
    LOADR(p, 12, (base) + 12) LOADR(p, 13, (base) + 13) LOADR(p, 14, (base) + 14) LOADR(p, 15, (base) + 15) \
    LOADR(p, 16, (base) + 16) LOADR(p, 17, (base) + 17) LOADR(p, 18, (base) + 18) LOADR(p, 19, (base) + 19) \
    LOADR(p, 20, (base) + 20) LOADR(p, 21, (base) + 21) LOADR(p, 22, (base) + 22) LOADR(p, 23, (base) + 23) \
    LOADR(p, 24, (base) + 24) LOADR(p, 25, (base) + 25) LOADR(p, 26, (base) + 26) LOADR(p, 27, (base) + 27) \
    LOADR(p, 28, (base) + 28) LOADR(p, 29, (base) + 29) LOADR(p, 30, (base) + 30) LOADR(p, 31, (base) + 31)

#define COMPU32(p, tb) \
    COMPU(p, 0)  COMPU(p, 1)  COMPU(p, 2)  COMPU(p, 3)  \
    COMPU(p, 4)  COMPU(p, 5)  COMPU(p, 6)  COMPU(p, 7)  \
    RESCALE_KILL((tb) + 7) \
    COMPU(p, 8)  COMPU(p, 9)  COMPU(p, 10) COMPU(p, 11) \
    COMPU(p, 12) COMPU(p, 13) COMPU(p, 14) COMPU(p, 15) \
    RESCALE_KILL((tb) + 15) \
    COMPU(p, 16) COMPU(p, 17) COMPU(p, 18) COMPU(p, 19) \
    COMPU(p, 20) COMPU(p, 21) COMPU(p, 22) COMPU(p, 23) \
    RESCALE_KILL((tb) + 23) \
    COMPU(p, 24) COMPU(p, 25) COMPU(p, 26) COMPU(p, 27) \
    COMPU(p, 28) COMPU(p, 29) COMPU(p, 30) COMPU(p, 31) \
    RESCALE_KILL((tb) + 31)

#define COMPA32(p, o) \
    COMPA(p, 0,  (o) + 0)  COMPA(p, 1,  (o) + 1)  COMPA(p, 2,  (o) + 2)  COMPA(p, 3,  (o) + 3)  \
    COMPA(p, 4,  (o) + 4)  COMPA(p, 5,  (o) + 5)  COMPA(p, 6,  (o) + 6)  COMPA(p, 7,  (o) + 7)  \
    RESCALE_KILL(t + (o) + 7) \
    COMPA(p, 8,  (o) + 8)  COMPA(p, 9,  (o) + 9)  COMPA(p, 10, (o) + 10) COMPA(p, 11, (o) + 11) \
    COMPA(p, 12, (o) + 12) COMPA(p, 13, (o) + 13) COMPA(p, 14, (o) + 14) COMPA(p, 15, (o) + 15) \
    RESCALE_KILL(t + (o) + 15) \
    COMPA(p, 16, (o) + 16) COMPA(p, 17, (o) + 17) COMPA(p, 18, (o) + 18) COMPA(p, 19, (o) + 19) \
    COMPA(p, 20, (o) + 20) COMPA(p, 21, (o) + 21) COMPA(p, 22, (o) + 22) COMPA(p, 23, (o) + 23) \
    RESCALE_KILL(t + (o) + 23) \
    COMPA(p, 24, (o) + 24) COMPA(p, 25, (o) + 25) COMPA(p, 26, (o) + 26) COMPA(p, 27, (o) + 27) \
    COMPA(p, 28, (o) + 28) COMPA(p, 29, (o) + 29) COMPA(p, 30, (o) + 30) COMPA(p, 31, (o) + 31) \
    RESCALE_KILL(t + (o) + 31)

#define DECL32(p) \
    DECL3(p, 0)  DECL3(p, 1)  DECL3(p, 2)  DECL3(p, 3)  DECL3(p, 4)  DECL3(p, 5)  DECL3(p, 6)  DECL3(p, 7)  \
    DECL3(p, 8)  DECL3(p, 9)  DECL3(p, 10) DECL3(p, 11) DECL3(p, 12) DECL3(p, 13) DECL3(p, 14) DECL3(p, 15) \
    DECL3(p, 16) DECL3(p, 17) DECL3(p, 18) DECL3(p, 19) DECL3(p, 20) DECL3(p, 21) DECL3(p, 22) DECL3(p, 23) \
    DECL3(p, 24) DECL3(p, 25) DECL3(p, 26) DECL3(p, 27) DECL3(p, 28) DECL3(p, 29) DECL3(p, 30) DECL3(p, 31)

__global__ __launch_bounds__(64, 1) void ctc_kernel(const float* __restrict__ G,
                                                    const int* __restrict__ targets,
                                                    const int* __restrict__ lens,
                                                    const int* __restrict__ tlens,
                                                    float* __restrict__ accum) {
  int b = blockIdx.x;
  int lane = threadIdx.x;
  const int* tgt = targets + b * Udim;
  int i1 = min(2 * lane, Udim - 1);
  int i3 = min(2 * lane + 1, Udim - 1);
  int l1 = tgt[i1];
  int l3 = tgt[i3];
  int lm1 = tgt[min(max(2 * lane - 1, 0), Udim - 1)];
  const float fm1 = ((lane >= 1) && (l1 != lm1)) ? 1.0f : 0.0f;  // skip1 mask
  const float fm3 = (l3 != l1) ? 1.0f : 0.0f;                    // skip3 mask
  int len = lens[b];
  int tl = tlens[b];
  const int end1 = 2 * tl - 1;       // readout states are end1 and end1+1
  const int base4 = 4 * lane;        // this lane owns states base4..base4+3
  const float* gb = G + (size_t)b * Tlen * GROW;

  // t=0 init (linear space): lane0's float4 = {p(tgt0), p(tgt1), blank, 0}
  float4 v0 = *(const float4*)(gb + 4 * lane);
  float a0 = (lane == 0) ? v0.z : 0.0f;
  float a1 = (lane == 0) ? v0.x : 0.0f;
  float a2 = 0.0f, a3 = 0.0f;
  int logScale = 0;

  DECL32(sA)
  DECL32(sB)

  // prime bank A with rows 1..32 (all valid: len >= 500)
  LOAD32(sA, 1)

  int steps = len - 1;               // recurrence covers t = 1 .. len-1
  int mainN = steps & ~63;           // floor to multiple of 64
  int t = 1;
  for (int blk = 0; blk < mainN; blk += 64) {
    // H0: refill bank B (rows t+32..t+63), consume bank A (steps t..t+31)
    LOAD32(sB, t + 32)
    __builtin_amdgcn_sched_barrier(0);
    COMPU32(sA, t)
    // H1: refill bank A (rows t+64..t+95), consume bank B (steps t+32..t+63)
    LOAD32(sA, t + 64)
    __builtin_amdgcn_sched_barrier(0);
    COMPU32(sB, t + 32)
    t += 64;
  }
  {
    // tail: up to 64 guarded steps. Bank A holds rows t..t+31 (loaded by the
    // last H1 or the prime); refill bank B for rows t+32..t+63 (over-reads
    // land in mapped ws; values discarded by the freeze masks).
    LOAD32(sB, t + 32)
    __builtin_amdgcn_sched_barrier(0);
    COMPA32(sA, 0)
    COMPA32(sB, 32)
  }

  __shared__ float fin[256];
  fin[4 * lane + 0] = a0;
  fin[4 * lane + 1] = a1;
  fin[4 * lane + 2] = a2;
  fin[4 * lane + 3] = a3;
  __syncthreads();
  if (lane == 0) {
    int end = 2 * tl;
    float sum = fin[end] + fin[end - 1];
    float loss = -LN2 * (log2f(sum) + (float)logScale);
    atomicAdd(&accum[0], 0.5f * loss);
  }
}

// ---------------- K5: finalize -- KL partial reduction + FP32 output -------
__global__ __launch_bounds__(1024) void finalize_kernel(const float* __restrict__ accum,
                                                        const float* __restrict__ klp,
                                                        float* __restrict__ out) {
  __shared__ float red[16];
  int tid = threadIdx.x;
  float s = 0.0f;
  for (int i = tid; i < 16 * Tlen; i += 1024) s += klp[i];
  s = dppSum64(s);
  int wave = tid >> 6, lane = tid & 63;
  if (lane == 63) red[wave] = s;
  __syncthreads();
  if (tid == 0) {
    float tot = 0.0f;
    #pragma unroll
    for (int w = 0; w < 16; ++w) tot += red[w];
    out[0] = accum[0];
    out[1] = 0.5f * tot;
  }
}

extern "C" void kernel_launch(void* const* d_in, const int* in_sizes, int n_in,
                              void* d_out, int out_size, void* d_ws, size_t ws_size,
                              hipStream_t stream) {
  const float* enc = (const float*)d_in[0];
  const float* W = (const float*)d_in[1];
  const float* bias = (const float*)d_in[2];
  const int* lens = (const int*)d_in[3];
  const int* targets = (const int*)d_in[4];
  const int* tlens = (const int*)d_in[5];

  char* ws = (char*)d_ws;
  u16* a_bf = (u16*)(ws + WS_ABF);
  u16* w_bf = (u16*)(ws + WS_WBF);
  u16* Zb   = (u16*)(ws + WS_Z);
  float* Gp  = (float*)(ws + WS_G);   // aliases a_bf (dead after gemm)
  float* klp = (float*)(ws + WS_KL);  // aliases w_bf (dead after gemm)
  float* accum = (float*)(ws + WS_ACC);

  hipLaunchKernelGGL(convert_kernel, dim3(1024), dim3(256), 0, stream,
                     (const float4*)enc, (const float4*)W, (uint4*)a_bf, (uint4*)w_bf,
                     lens, accum);
  hipLaunchKernelGGL(gemm_kernel, dim3(4000), dim3(256), 0, stream,
                     a_bf, w_bf, lens, Zb);
  hipLaunchKernelGGL(cr_stats_kernel, dim3(16, 1000), dim3(256), 0, stream,
                     Zb, bias, lens, targets, tlens, Gp, klp);
  hipLaunchKernelGGL(ctc_kernel, dim3(Bsz), dim3(64), 0, stream,
                     Gp, targets, lens, tlens, accum);
  hipLaunchKernelGGL(finalize_kernel, dim3(1), dim3(1024), 0, stream,
                     accum, klp, (float*)d_out);
}